// Round 11
// baseline (155.487 us; speedup 1.0000x reference)
//
#include <hip/hip_runtime.h>
#include <hip/hip_bf16.h>
#include <math.h>

typedef __attribute__((ext_vector_type(8))) __bf16 bf16x8;
typedef __attribute__((ext_vector_type(4))) __bf16 bf16x4;
typedef __attribute__((ext_vector_type(4))) float f32x4;

#define NTOK 4096
#define DHEAD 32
#define MBIAS 12.0f
#define QSCALE 0.2550316626f   // log2(e)/sqrt(32)
#define NSP 8                  // kv splits (across blocks)

static __device__ __forceinline__ float fexp2(float x) {
    return __builtin_amdgcn_exp2f(x);
}

// XOR swizzle: bijective within tile, spreads rows across 16B bank slots.
#define SWZ(byte, row) ((byte) ^ (((row) & 7) << 4))

// ---------------- Kernel 1: fused QKV projection (fp32 x and w, split-bf16 MFMA) ----------------
// (R9 version — in-loop hi/lo conversion; split_x was net-negative in R10.)
__global__ __launch_bounds__(256, 4) void qkv_mfma_kernel(const float* __restrict__ x,
                                                          const float* __restrict__ w,
                                                          __bf16* __restrict__ Qo,
                                                          __bf16* __restrict__ Ko,
                                                          __bf16* __restrict__ Vo)
{
    const int bid   = blockIdx.x;        // 1536 = 6 otiles * 256 ntiles
    const int ot    = bid % 6;
    const int ntile = bid / 6;
    const int tid   = threadIdx.x;
    const int wv    = tid >> 6, lane = tid & 63;
    const int g = lane >> 4, ql = lane & 15;
    const int o0 = ot * 64 + wv * 16;
    const int n0 = ntile * 32;

    f32x4 acc[2] = {{0.f,0.f,0.f,0.f},{0.f,0.f,0.f,0.f}};

    #pragma unroll
    for (int kc = 0; kc < 4; ++kc) {
        const float* wp = w + (size_t)(o0 + ql) * 128 + kc * 32 + g * 8;
        f32x4 w0 = *(const f32x4*)wp;
        f32x4 w1 = *(const f32x4*)(wp + 4);
        bf16x8 wh, wl;
        #pragma unroll
        for (int i = 0; i < 4; ++i) {
            float v0 = w0[i], v1 = w1[i];
            __bf16 h0 = (__bf16)v0, h1 = (__bf16)v1;
            wh[i] = h0; wh[4 + i] = h1;
            wl[i] = (__bf16)(v0 - (float)h0);
            wl[4 + i] = (__bf16)(v1 - (float)h1);
        }
        #pragma unroll
        for (int nt = 0; nt < 2; ++nt) {
            const int ng = n0 + nt * 16 + ql;
            const int b = ng >> 12, nn = ng & (NTOK - 1);
            const float* xp = x + ((size_t)b * 128 + kc * 32 + g * 8) * NTOK + nn;
            bf16x8 bh, bl;
            #pragma unroll
            for (int i = 0; i < 8; ++i) {
                float v = xp[(size_t)i * NTOK];
                __bf16 h = (__bf16)v;
                bh[i] = h;
                bl[i] = (__bf16)(v - (float)h);
            }
            acc[nt] = __builtin_amdgcn_mfma_f32_16x16x32_bf16(wh, bh, acc[nt], 0, 0, 0);
            acc[nt] = __builtin_amdgcn_mfma_f32_16x16x32_bf16(wl, bh, acc[nt], 0, 0, 0);
            acc[nt] = __builtin_amdgcn_mfma_f32_16x16x32_bf16(wh, bl, acc[nt], 0, 0, 0);
        }
    }

    const int orow = o0 + 4 * g;   // +r ; branch uniform per wave (64-aligned o splits)
    #pragma unroll
    for (int nt = 0; nt < 2; ++nt) {
        const int ng = n0 + nt * 16 + ql;
        const int b = ng >> 12, nn = ng & (NTOK - 1);
        if (orow < 128) {
            const int h = orow >> 5, d0 = orow & 31;
            bf16x4 q4;
            #pragma unroll
            for (int r = 0; r < 4; ++r) q4[r] = (__bf16)(acc[nt][r] * QSCALE);
            *(bf16x4*)(Qo + ((size_t)(b * 4 + h) * NTOK + nn) * DHEAD + d0) = q4;
        } else if (orow < 256) {
            const int oo = orow - 128, h = oo >> 5, d0 = oo & 31;
            bf16x4 k4;
            #pragma unroll
            for (int r = 0; r < 4; ++r) k4[r] = (__bf16)acc[nt][r];
            *(bf16x4*)(Ko + ((size_t)(b * 4 + h) * NTOK + nn) * DHEAD + d0) = k4;
        } else {
            const int oo = orow - 256, h = oo >> 5, d0 = oo & 31;
            #pragma unroll
            for (int r = 0; r < 4; ++r)
                Vo[((size_t)(b * 4 + h) * DHEAD + d0 + r) * NTOK + nn] = (__bf16)acc[nt][r];
        }
    }
}

// ---------------- Kernel 2: flash attention, LDS-staged K/V, q-split waves, kv-split blocks ----------------
// 512 blocks (8 bh x 8 qb x 8 sp) x 512 thr. Wave wv owns q-rows [qb*512+wv*64, +64) over
// kv chunk [sp*512, +512). K/V staged per 64-kv tile into 16 KB LDS double-buffer
// (XOR-swizzled: linear layout is 8/16-way bank conflict), reg-staged issue-early/write-late.
// Global K/V traffic 256 MB -> 32 MB (R10 diagnosis: L2->CU BW-bound at ~3x supply).
// Partials (additive: static MBIAS) -> global slices, no atomics; combined by combine_kernel.
__global__ __launch_bounds__(512, 4) void attn_kernel(const __bf16* __restrict__ Q,
                                                      const __bf16* __restrict__ K,
                                                      const __bf16* __restrict__ VT,
                                                      float* __restrict__ opart,
                                                      float* __restrict__ lpart)
{
    __shared__ __align__(16) char smem[2][8192];   // per buf: K 64x32 bf16 (4KB) | V^T 32x64 bf16 (4KB)
    const int bid = blockIdx.x;      // 512
    const int sp  = bid & 7;
    const int qb  = (bid >> 3) & 7;
    const int bh  = bid >> 6;
    const int tid = threadIdx.x;
    const int wv  = tid >> 6;
    const int lane = tid & 63;
    const int g = lane >> 4, ql = lane & 15;
    const __bf16* Qb = Q  + (size_t)bh * NTOK * DHEAD;
    const __bf16* Kb = K  + (size_t)bh * NTOK * DHEAD;
    const __bf16* Vb = VT + (size_t)bh * DHEAD * NTOK;
    const int q0  = qb * 512 + wv * 64;
    const int kv0 = sp * 512;

    // staging role (wave-uniform: waves 0-3 stage K, 4-7 stage V); 16 B per thread per tile
    const __bf16* sSrc;
    int sDst, sAdv;
    if (tid < 256) {
        const int row = tid >> 2, col = tid & 3;
        sSrc = Kb + (size_t)(kv0 + row) * DHEAD + col * 8;
        sDst = SWZ(row * 64 + col * 16, row);
        sAdv = 64 * DHEAD;                    // +64 kv rows per tile
    } else {
        const int t2 = tid - 256, row = t2 >> 3, col = t2 & 7;
        sSrc = Vb + (size_t)row * NTOK + kv0 + col * 8;
        sDst = 4096 + SWZ(row * 128 + col * 16, row);
        sAdv = 64;                            // +64 kv cols per tile
    }

    bf16x8 qf[4];
    #pragma unroll
    for (int qt = 0; qt < 4; ++qt)
        qf[qt] = *(const bf16x8*)(Qb + (size_t)(q0 + qt * 16 + ql) * DHEAD + 8 * g);

    f32x4 acc[4][2] = {};
    float lsum[4] = {0.f, 0.f, 0.f, 0.f};
    const f32x4 mneg = {-MBIAS, -MBIAS, -MBIAS, -MBIAS};

    // prologue: stage tile 0 into buf 0
    bf16x8 sreg = *(const bf16x8*)sSrc;
    *(bf16x8*)(smem[0] + sDst) = sreg;
    __syncthreads();

    for (int t = 0; t < 8; ++t) {
        const int cur = t & 1;
        if (t < 7) sreg = *(const bf16x8*)(sSrc + (size_t)(t + 1) * sAdv);   // issue early (T14)
        const char* kb  = smem[cur];
        const char* vbp = smem[cur] + 4096;

        #pragma unroll
        for (int s = 0; s < 2; ++s) {
            const int r0 = s * 32 + ql, r1 = s * 32 + 16 + ql;
            bf16x8 kf0 = *(const bf16x8*)(kb + SWZ(r0 * 64 + g * 16, r0));
            bf16x8 kf1 = *(const bf16x8*)(kb + SWZ(r1 * 64 + g * 16, r1));
            const int voff = s * 64 + g * 8;
            bf16x4 va00 = *(const bf16x4*)(vbp + SWZ(ql * 128 + voff, ql));
            bf16x4 va01 = *(const bf16x4*)(vbp + SWZ(ql * 128 + voff + 32, ql));
            bf16x4 va10 = *(const bf16x4*)(vbp + SWZ((16 + ql) * 128 + voff, 16 + ql));
            bf16x4 va11 = *(const bf16x4*)(vbp + SWZ((16 + ql) * 128 + voff + 32, 16 + ql));
            // V^T A-fragments: slot j<4 -> local kv s*32+4g+j ; j>=4 -> s*32+16+4g+(j-4)
            bf16x8 vf0 = __builtin_shufflevector(va00, va01, 0,1,2,3,4,5,6,7);
            bf16x8 vf1 = __builtin_shufflevector(va10, va11, 0,1,2,3,4,5,6,7);

            #pragma unroll
            for (int qt = 0; qt < 4; ++qt) {
                f32x4 s0 = __builtin_amdgcn_mfma_f32_16x16x32_bf16(kf0, qf[qt], mneg, 0, 0, 0);
                f32x4 s1 = __builtin_amdgcn_mfma_f32_16x16x32_bf16(kf1, qf[qt], mneg, 0, 0, 0);
                bf16x8 pf;
                float ps = 0.f;
                #pragma unroll
                for (int r = 0; r < 4; ++r) {
                    float e0 = fexp2(s0[r]);
                    float e1 = fexp2(s1[r]);
                    ps += e0 + e1;
                    pf[r]     = (__bf16)e0;
                    pf[4 + r] = (__bf16)e1;
                }
                lsum[qt] += ps;
                acc[qt][0] = __builtin_amdgcn_mfma_f32_16x16x32_bf16(vf0, pf, acc[qt][0], 0, 0, 0);
                acc[qt][1] = __builtin_amdgcn_mfma_f32_16x16x32_bf16(vf1, pf, acc[qt][1], 0, 0, 0);
            }
        }

        if (t < 7) *(bf16x8*)(smem[cur ^ 1] + sDst) = sreg;   // write late, other buffer
        __syncthreads();
    }

    // l: reduce across the 4 g-groups holding each q-col
    #pragma unroll
    for (int qt = 0; qt < 4; ++qt) {
        lsum[qt] += __shfl_xor(lsum[qt], 16);
        lsum[qt] += __shfl_xor(lsum[qt], 32);
    }

    // write fp32 partials to this split's slice (disjoint -> no atomics)
    float* ob = opart + (size_t)(sp * 8 + bh) * 32 * NTOK;
    float* lp = lpart + (size_t)(sp * 8 + bh) * NTOK;
    #pragma unroll
    for (int qt = 0; qt < 4; ++qt) {
        const int q = q0 + qt * 16 + ql;
        #pragma unroll
        for (int dt = 0; dt < 2; ++dt)
            #pragma unroll
            for (int r = 0; r < 4; ++r)
                ob[(size_t)(dt * 16 + 4 * g + r) * NTOK + q] = acc[qt][dt][r];
        if (g == 0) lp[q] = lsum[qt];
    }
}

// ---------------- Kernel 3: combine kv-split partials -> normalized fp32 out^T ----------------
__global__ __launch_bounds__(256) void combine_kernel(const float* __restrict__ opart,
                                                      const float* __restrict__ lpart,
                                                      float* __restrict__ ot)
{
    const int gid = blockIdx.x * 256 + threadIdx.x;   // 262144 threads, 4 floats each
    const int q   = (gid * 4) & (NTOK - 1);
    const int row = gid >> 10;                        // bh*32 + d in [0,256)
    const int bh  = row >> 5;
    f32x4 l4 = {0.f,0.f,0.f,0.f}, o4 = {0.f,0.f,0.f,0.f};
    #pragma unroll
    for (int sp = 0; sp < NSP; ++sp) {
        l4 += *(const f32x4*)(lpart + (size_t)(sp * 8 + bh) * NTOK + q);
        o4 += *(const f32x4*)(opart + ((size_t)sp * 256 + row) * NTOK + q);
    }
    f32x4 r;
    #pragma unroll
    for (int i = 0; i < 4; ++i) r[i] = o4[i] / l4[i];
    *(f32x4*)(ot + (size_t)row * NTOK + q) = r;
}

// ---------------- Kernel 4: output projection (fp32 ot and w, split-bf16 MFMA) + bias ----------------
__global__ __launch_bounds__(256, 4) void out_mfma_kernel(const float* __restrict__ ot,
                                                          const float* __restrict__ w,
                                                          const float* __restrict__ bias,
                                                          float* __restrict__ y)
{
    const int bid   = blockIdx.x;        // 1024 = 2 otiles * 512 ntiles
    const int otile = bid & 1;
    const int ntile = bid >> 1;
    const int tid   = threadIdx.x;
    const int wv    = tid >> 6, lane = tid & 63;
    const int g = lane >> 4, ql = lane & 15;
    const int o0 = otile * 64 + wv * 16;
    const int n0 = ntile * 16;

    f32x4 acc = {0.f,0.f,0.f,0.f};
    const int ng = n0 + ql;
    const int b = ng >> 12, nn = ng & (NTOK - 1);

    #pragma unroll
    for (int kc = 0; kc < 4; ++kc) {
        const float* wp = w + (size_t)(o0 + ql) * 128 + kc * 32 + g * 8;
        f32x4 w0 = *(const f32x4*)wp;
        f32x4 w1 = *(const f32x4*)(wp + 4);
        bf16x8 wh, wl;
        #pragma unroll
        for (int i = 0; i < 4; ++i) {
            float v0 = w0[i], v1 = w1[i];
            __bf16 h0 = (__bf16)v0, h1 = (__bf16)v1;
            wh[i] = h0; wh[4 + i] = h1;
            wl[i] = (__bf16)(v0 - (float)h0);
            wl[4 + i] = (__bf16)(v1 - (float)h1);
        }
        // ot channel c = kc*32 + g*8 + i lives at row (b*4+kc)*32 + g*8 + i
        const float* op = ot + (((size_t)(b * 4 + kc)) * 32 + g * 8) * NTOK + nn;
        bf16x8 bh, bl;
        #pragma unroll
        for (int i = 0; i < 8; ++i) {
            float v = op[(size_t)i * NTOK];
            __bf16 h = (__bf16)v;
            bh[i] = h;
            bl[i] = (__bf16)(v - (float)h);
        }
        acc = __builtin_amdgcn_mfma_f32_16x16x32_bf16(wh, bh, acc, 0, 0, 0);
        acc = __builtin_amdgcn_mfma_f32_16x16x32_bf16(wl, bh, acc, 0, 0, 0);
        acc = __builtin_amdgcn_mfma_f32_16x16x32_bf16(wh, bl, acc, 0, 0, 0);
    }

    const int orow = o0 + 4 * g;
    #pragma unroll
    for (int r = 0; r < 4; ++r)
        y[((size_t)b * 128 + orow + r) * NTOK + nn] = acc[r] + bias[orow + r];
}

extern "C" void kernel_launch(void* const* d_in, const int* in_sizes, int n_in,
                              void* d_out, int out_size, void* d_ws, size_t ws_size,
                              hipStream_t stream) {
    const float* x     = (const float*)d_in[0];
    const float* w_qkv = (const float*)d_in[1];
    const float* w_out = (const float*)d_in[2];
    const float* b_out = (const float*)d_in[3];
    float* y = (float*)d_out;

    // ws layout (43.125 MB): Q 2M | K 2M | VT 2M | ot 4M | lpart 1M | opart 32M
    char* ws = (char*)d_ws;
    __bf16* Qb    = (__bf16*)(ws);
    __bf16* Kb    = (__bf16*)(ws + (size_t)2  * 1024 * 1024);
    __bf16* Vb    = (__bf16*)(ws + (size_t)4  * 1024 * 1024);
    float*  ob    = (float*) (ws + (size_t)6  * 1024 * 1024);
    float*  lpart = (float*) (ws + (size_t)10 * 1024 * 1024);
    float*  opart = (float*) (ws + (size_t)11 * 1024 * 1024);

    hipLaunchKernelGGL(qkv_mfma_kernel, dim3(1536), dim3(256), 0, stream, x, w_qkv, Qb, Kb, Vb);
    hipLaunchKernelGGL(attn_kernel, dim3(512), dim3(512), 0, stream, Qb, Kb, Vb, opart, lpart);
    hipLaunchKernelGGL(combine_kernel, dim3(1024), dim3(256), 0, stream, opart, lpart, ob);
    hipLaunchKernelGGL(out_mfma_kernel, dim3(1024), dim3(256), 0, stream, ob, w_out, b_out, y);
}